// Round 1
// baseline (117.963 us; speedup 1.0000x reference)
//
#include <hip/hip_runtime.h>

// MonotoneActivation: B=4096, G=512, K=4, D=8
// out[b, g*8+d] = sum_j coef_j * params[g, idx_j, d]
// where v sorted ascending with orig indices i_j,
// coef_0 = v0, coef_j = v_j - v_{j-1},
// idx_0 = 15, idx_{j+1} = idx_j - 2^{i_j}.

#define BB 4096
#define GG 512

__global__ __launch_bounds__(256) void monoact_kernel(
    const float4* __restrict__ X4,   // B*G entries (each = 4 floats of one (b,g))
    const float4* __restrict__ P4,   // params as float4: G*16*2
    float4* __restrict__ O4)         // out as float4: B*G*2
{
    const unsigned t = blockIdx.x * blockDim.x + threadIdx.x; // flat (b,g)
    const float4 x = X4[t];

    float v[4] = {x.x, x.y, x.z, x.w};
    int   id[4] = {0, 1, 2, 3};

    // 5-comparator sorting network for 4 elems (ascending).
    // Tie order is irrelevant: tied coefs are 0 and prefix index-sets
    // are order-invariant across ties.
#define CSWAP(a, b)                                               \
    {                                                             \
        bool sw = v[a] > v[b];                                    \
        float tv = sw ? v[a] : v[b];                              \
        v[a] = sw ? v[b] : v[a];                                  \
        v[b] = tv;                                                \
        int ti = sw ? id[a] : id[b];                              \
        id[a] = sw ? id[b] : id[a];                               \
        id[b] = ti;                                               \
    }
    CSWAP(0, 1)
    CSWAP(2, 3)
    CSWAP(0, 2)
    CSWAP(1, 3)
    CSWAP(1, 2)
#undef CSWAP

    const float c0 = v[0];
    const float c1 = v[1] - v[0];
    const float c2 = v[2] - v[1];
    const float c3 = v[3] - v[2];

    const int r0 = 15;
    const int r1 = r0 - (1 << id[0]);
    const int r2 = r1 - (1 << id[1]);
    const int r3 = r2 - (1 << id[2]);

    const unsigned g = t & (GG - 1);
    const float4* pg = P4 + ((size_t)g << 5); // g*16 rows * 2 float4/row

    const float4 a0 = pg[r0 * 2], a0h = pg[r0 * 2 + 1];
    const float4 a1 = pg[r1 * 2], a1h = pg[r1 * 2 + 1];
    const float4 a2 = pg[r2 * 2], a2h = pg[r2 * 2 + 1];
    const float4 a3 = pg[r3 * 2], a3h = pg[r3 * 2 + 1];

    float4 o0, o1;
    o0.x = fmaf(c0, a0.x, fmaf(c1, a1.x, fmaf(c2, a2.x, c3 * a3.x)));
    o0.y = fmaf(c0, a0.y, fmaf(c1, a1.y, fmaf(c2, a2.y, c3 * a3.y)));
    o0.z = fmaf(c0, a0.z, fmaf(c1, a1.z, fmaf(c2, a2.z, c3 * a3.z)));
    o0.w = fmaf(c0, a0.w, fmaf(c1, a1.w, fmaf(c2, a2.w, c3 * a3.w)));
    o1.x = fmaf(c0, a0h.x, fmaf(c1, a1h.x, fmaf(c2, a2h.x, c3 * a3h.x)));
    o1.y = fmaf(c0, a0h.y, fmaf(c1, a1h.y, fmaf(c2, a2h.y, c3 * a3h.y)));
    o1.z = fmaf(c0, a0h.z, fmaf(c1, a1h.z, fmaf(c2, a2h.z, c3 * a3h.z)));
    o1.w = fmaf(c0, a0h.w, fmaf(c1, a1h.w, fmaf(c2, a2h.w, c3 * a3h.w)));

    O4[2 * t]     = o0;
    O4[2 * t + 1] = o1;
}

extern "C" void kernel_launch(void* const* d_in, const int* in_sizes, int n_in,
                              void* d_out, int out_size, void* d_ws, size_t ws_size,
                              hipStream_t stream) {
    const float4* X4 = (const float4*)d_in[0];   // X: (4096, 2048) fp32
    const float4* P4 = (const float4*)d_in[1];   // params: (512, 16, 8) fp32
    float4* O4 = (float4*)d_out;                 // out: (4096, 4096) fp32

    const int total = BB * GG;                   // one thread per (b,g)
    const int block = 256;
    const int grid = total / block;              // 8192
    monoact_kernel<<<grid, block, 0, stream>>>(X4, P4, O4);
}

// Round 2
// 95.151 us; speedup vs baseline: 1.2397x; 1.2397x over previous
//
#include <hip/hip_runtime.h>

// MonotoneActivation: B=4096, G=512, K=4, D=8
// out[b, g*8+d] = sum_j coef_j * params[g, idx_j, d]
// Round 2: LDS-staged params per block to kill gather address divergence.
// Block = 256 threads = 16 g x 16 b, looping 4 b-tiles (64 b per block).
// LDS layout padded: g stride = 33 float4 (528 B) so ds_read_b128 base banks
// stagger over 8 groups (8-cycle floor instead of 16-way serialization).

#define BB 4096
#define GG 512
#define G_TILE 16
#define B_TILE 16
#define NB 4            // b-iterations per block; block covers 64 b
#define G_STRIDE 33     // float4 per g in LDS (32 + 1 pad)

__global__ __launch_bounds__(256) void monoact_kernel(
    const float4* __restrict__ X4,   // (B, 512) float4 view of X (B, 2048) fp32
    const float4* __restrict__ P4,   // (G, 32) float4 view of params (G,16,8) fp32
    float4* __restrict__ O4)         // (B, 1024) float4 view of out (B, 4096) fp32
{
    __shared__ float4 lds_p[G_TILE * G_STRIDE];   // 8448 B

    const int tid = threadIdx.x;
    const int g0 = blockIdx.x * G_TILE;
    const int b0 = blockIdx.y * (B_TILE * NB);

    // Stage params[g0..g0+15] (512 float4) into LDS, padded layout.
    // flat j in [0,512): g_l = j>>5, r = (j&31)>>1, h = j&1
    for (int j = tid; j < G_TILE * 32; j += 256) {
        const int g_l = j >> 5;
        const int rem = j & 31;
        const int r = rem >> 1;
        const int h = rem & 1;
        lds_p[g_l * G_STRIDE + r * 2 + h] = P4[(size_t)(g0 + g_l) * 32 + rem];
    }
    __syncthreads();

    const int g_l = tid & (G_TILE - 1);
    const int b_l = tid >> 4;
    const int g = g0 + g_l;
    const float4* __restrict__ pg = lds_p + g_l * G_STRIDE;

    for (int it = 0; it < NB; ++it) {
        const int b = b0 + it * B_TILE + b_l;

        const float4 x = X4[(size_t)b * 512 + g];

        float v[4] = {x.x, x.y, x.z, x.w};
        int   id[4] = {0, 1, 2, 3};
#define CSWAP(a, c)                                               \
        {                                                         \
            bool sw = v[a] > v[c];                                \
            float tv = sw ? v[a] : v[c];                          \
            v[a] = sw ? v[c] : v[a];                              \
            v[c] = tv;                                            \
            int ti = sw ? id[a] : id[c];                          \
            id[a] = sw ? id[c] : id[a];                           \
            id[c] = ti;                                           \
        }
        CSWAP(0, 1)
        CSWAP(2, 3)
        CSWAP(0, 2)
        CSWAP(1, 3)
        CSWAP(1, 2)
#undef CSWAP

        const float c0 = v[0];
        const float c1 = v[1] - v[0];
        const float c2 = v[2] - v[1];
        const float c3 = v[3] - v[2];

        const int r0 = 15;
        const int r1 = r0 - (1 << id[0]);
        const int r2 = r1 - (1 << id[1]);
        const int r3 = r2 - (1 << id[2]);

        const float4 a0 = pg[r0 * 2],     a0h = pg[r0 * 2 + 1];
        const float4 a1 = pg[r1 * 2],     a1h = pg[r1 * 2 + 1];
        const float4 a2 = pg[r2 * 2],     a2h = pg[r2 * 2 + 1];
        const float4 a3 = pg[r3 * 2],     a3h = pg[r3 * 2 + 1];

        float4 o0, o1;
        o0.x = fmaf(c0, a0.x, fmaf(c1, a1.x, fmaf(c2, a2.x, c3 * a3.x)));
        o0.y = fmaf(c0, a0.y, fmaf(c1, a1.y, fmaf(c2, a2.y, c3 * a3.y)));
        o0.z = fmaf(c0, a0.z, fmaf(c1, a1.z, fmaf(c2, a2.z, c3 * a3.z)));
        o0.w = fmaf(c0, a0.w, fmaf(c1, a1.w, fmaf(c2, a2.w, c3 * a3.w)));
        o1.x = fmaf(c0, a0h.x, fmaf(c1, a1h.x, fmaf(c2, a2h.x, c3 * a3h.x)));
        o1.y = fmaf(c0, a0h.y, fmaf(c1, a1h.y, fmaf(c2, a2h.y, c3 * a3h.y)));
        o1.z = fmaf(c0, a0h.z, fmaf(c1, a1h.z, fmaf(c2, a2h.z, c3 * a3h.z)));
        o1.w = fmaf(c0, a0h.w, fmaf(c1, a1h.w, fmaf(c2, a2h.w, c3 * a3h.w)));

        float4* __restrict__ o = O4 + (size_t)b * 1024 + (size_t)g * 2;
        o[0] = o0;
        o[1] = o1;
    }
}

extern "C" void kernel_launch(void* const* d_in, const int* in_sizes, int n_in,
                              void* d_out, int out_size, void* d_ws, size_t ws_size,
                              hipStream_t stream) {
    const float4* X4 = (const float4*)d_in[0];   // X: (4096, 2048) fp32
    const float4* P4 = (const float4*)d_in[1];   // params: (512, 16, 8) fp32
    float4* O4 = (float4*)d_out;                 // out: (4096, 4096) fp32

    dim3 grid(GG / G_TILE, BB / (B_TILE * NB));  // (32, 64) = 2048 blocks
    monoact_kernel<<<grid, 256, 0, stream>>>(X4, P4, O4);
}

// Round 3
// 94.890 us; speedup vs baseline: 1.2432x; 1.0028x over previous
//
#include <hip/hip_runtime.h>

// MonotoneActivation: B=4096, G=512, K=4, D=8
// out[b, g*8+d] = sum_j coef_j * params[g, idx_j, d]
// Round 3: one thread per OUTPUT float4 (2 threads per (b,g), h = D-half).
// Stores are now fully dense: 32 consecutive lanes write 512 contiguous bytes
// (16 B/lane at 16 B stride) instead of 2 half-dense 32 B-strided stores.
// Sort network duplicated across the lane pair (VALU is ~6%, don't care).

#define BB 4096
#define GG 512
#define G_TILE 16
#define NB 8            // b-iterations per block; 8 b-rows per iter -> 64 b per block
#define G_STRIDE 33     // float4 per g in LDS (32 + 1 pad) -> base banks spread mod 8

__global__ __launch_bounds__(256) void monoact_kernel(
    const float4* __restrict__ X4,   // (B, 512) float4 view of X (B, 2048) fp32
    const float4* __restrict__ P4,   // (G, 32) float4 view of params (G,16,8) fp32
    float4* __restrict__ O4)         // (B, 1024) float4 view of out (B, 4096) fp32
{
    __shared__ float4 lds_p[G_TILE * G_STRIDE];   // 8448 B

    const int tid = threadIdx.x;
    const int g0 = blockIdx.x * G_TILE;
    const int b0 = blockIdx.y * (8 * NB);

    // Stage params[g0..g0+15] (512 float4) into LDS, padded layout.
    for (int j = tid; j < G_TILE * 32; j += 256) {
        const int g_l = j >> 5;
        const int rem = j & 31;
        lds_p[g_l * G_STRIDE + rem] = P4[(size_t)(g0 + g_l) * 32 + rem];
    }
    __syncthreads();

    const int gh  = tid & 31;        // g_l*2 + h
    const int g_l = gh >> 1;
    const int h   = gh & 1;          // which D-half (float4) of the output row
    const int b_l = tid >> 5;        // 0..7
    const int g = g0 + g_l;
    const float4* __restrict__ pg = lds_p + g_l * G_STRIDE + h;

    for (int it = 0; it < NB; ++it) {
        const int b = b0 + it * 8 + b_l;

        const float4 x = X4[(size_t)b * 512 + g];   // lane pair shares this line

        float v[4] = {x.x, x.y, x.z, x.w};
        int   id[4] = {0, 1, 2, 3};
#define CSWAP(a, c)                                               \
        {                                                         \
            bool sw = v[a] > v[c];                                \
            float tv = sw ? v[a] : v[c];                          \
            v[a] = sw ? v[c] : v[a];                              \
            v[c] = tv;                                            \
            int ti = sw ? id[a] : id[c];                          \
            id[a] = sw ? id[c] : id[a];                           \
            id[c] = ti;                                           \
        }
        CSWAP(0, 1)
        CSWAP(2, 3)
        CSWAP(0, 2)
        CSWAP(1, 3)
        CSWAP(1, 2)
#undef CSWAP

        const float c0 = v[0];
        const float c1 = v[1] - v[0];
        const float c2 = v[2] - v[1];
        const float c3 = v[3] - v[2];

        const int r0 = 15;
        const int r1 = r0 - (1 << id[0]);
        const int r2 = r1 - (1 << id[1]);
        const int r3 = r2 - (1 << id[2]);

        const float4 a0 = pg[r0 * 2];
        const float4 a1 = pg[r1 * 2];
        const float4 a2 = pg[r2 * 2];
        const float4 a3 = pg[r3 * 2];

        float4 o;
        o.x = fmaf(c0, a0.x, fmaf(c1, a1.x, fmaf(c2, a2.x, c3 * a3.x)));
        o.y = fmaf(c0, a0.y, fmaf(c1, a1.y, fmaf(c2, a2.y, c3 * a3.y)));
        o.z = fmaf(c0, a0.z, fmaf(c1, a1.z, fmaf(c2, a2.z, c3 * a3.z)));
        o.w = fmaf(c0, a0.w, fmaf(c1, a1.w, fmaf(c2, a2.w, c3 * a3.w)));

        // 32 consecutive lanes -> 512 B fully-dense contiguous store per b-row.
        O4[(size_t)b * 1024 + (size_t)g0 * 2 + gh] = o;
    }
}

extern "C" void kernel_launch(void* const* d_in, const int* in_sizes, int n_in,
                              void* d_out, int out_size, void* d_ws, size_t ws_size,
                              hipStream_t stream) {
    const float4* X4 = (const float4*)d_in[0];   // X: (4096, 2048) fp32
    const float4* P4 = (const float4*)d_in[1];   // params: (512, 16, 8) fp32
    float4* O4 = (float4*)d_out;                 // out: (4096, 4096) fp32

    dim3 grid(GG / G_TILE, BB / (8 * NB));       // (32, 64) = 2048 blocks
    monoact_kernel<<<grid, 256, 0, stream>>>(X4, P4, O4);
}